// Round 7
// baseline (129.323 us; speedup 1.0000x reference)
//
#include <hip/hip_runtime.h>
#include <hip/hip_bf16.h>

// ============================================================================
// R7: K2 ROW-CHUNK experiment (model discrimination):
//   service-bound model  -> no change (bytes identical)  => K2 is at roofline
//   latency-chain model  -> K2 23 -> ~14us               => keep structure
// Each wave handles RCHUNK=8 consecutive rows: one coalesced row_ptr load
// (shfl-distributed), cols/vals L1-hot across rows (contiguous edge ranges),
// per-row marginal chain ~1 round trip instead of 3. Gather pattern, byte
// volume, arithmetic: identical to R6.
// Known splits: fills ~90us fixed, K1 ~10us (floor ~7), K2 ~23us.
// ============================================================================
#define D 128
#define RCHUNK 8
#define GEMM_ROWS 32    // fallback tier only

typedef __bf16 bf16x8 __attribute__((ext_vector_type(8)));
typedef float  f32x4  __attribute__((ext_vector_type(4)));
typedef float  f32x2  __attribute__((ext_vector_type(2)));
typedef unsigned int u32x4 __attribute__((ext_vector_type(4)));

__device__ inline bf16x8 cvt_a8(const float* __restrict__ p) {
    float4 v0 = ((const float4*)p)[0], v1 = ((const float4*)p)[1];
    bf16x8 a;
    a[0] = (__bf16)v0.x; a[1] = (__bf16)v0.y; a[2] = (__bf16)v0.z; a[3] = (__bf16)v0.w;
    a[4] = (__bf16)v1.x; a[5] = (__bf16)v1.y; a[6] = (__bf16)v1.z; a[7] = (__bf16)v1.w;
    return a;
}

// ---------------------------------------------------------------------------
// K1: fused GEMM + row_ptr (UNCHANGED control; bf16 h).
// ---------------------------------------------------------------------------
__global__ __launch_bounds__(256) void fused_gemm_rp(
        const float* __restrict__ x, const float* __restrict__ w,
        const int* __restrict__ rows,
        unsigned short* __restrict__ h, int* __restrict__ rp,
        int n_nodes, int n_edges, int gemm_blocks) {
    const int b = blockIdx.x;

    if (b >= gemm_blocks) {           // ---- row_ptr builder blocks ----
        int e = (b - gemm_blocks) * 256 + threadIdx.x;
        if (e >= n_edges) return;
        int r    = rows[e];
        int prev = (e == 0) ? -1 : rows[e - 1];
        for (int rr = prev + 1; rr <= r; ++rr) rp[rr] = e;
        if (e == n_edges - 1)
            for (int rr = r + 1; rr <= n_nodes; ++rr) rp[rr] = n_edges;
        return;
    }

    const int wave = threadIdx.x >> 6;
    const int lane = threadIdx.x & 63;
    const int m16  = lane & 15;
    const int q    = lane >> 4;

    const int row0 = b * 64;
    const int col0 = wave * 32;

    bf16x8 bfr[2][4];
#pragma unroll
    for (int t = 0; t < 2; ++t)
#pragma unroll
        for (int s = 0; s < 4; ++s) {
            const float* wp = w + (size_t)(32 * s + q * 8) * D + col0 + 16 * t + m16;
#pragma unroll
            for (int j = 0; j < 8; ++j)
                bfr[t][s][j] = (__bf16)wp[(size_t)j * D];
        }

#pragma unroll 1
    for (int sl = 0; sl < 4; ++sl) {
        const int r = row0 + sl * 16 + m16;
        const float* xp = x + (size_t)r * D + q * 8;

        bf16x8 a[4];
        if (r < n_nodes) {
#pragma unroll
            for (int s = 0; s < 4; ++s) a[s] = cvt_a8(xp + 32 * s);
        } else {
#pragma unroll
            for (int s = 0; s < 4; ++s)
#pragma unroll
                for (int j = 0; j < 8; ++j) a[s][j] = (__bf16)0.f;
        }

        f32x4 acc0 = (f32x4)0.f, acc1 = (f32x4)0.f;
#pragma unroll
        for (int s = 0; s < 4; ++s) {
            acc0 = __builtin_amdgcn_mfma_f32_16x16x32_bf16(a[s], bfr[0][s], acc0, 0, 0, 0);
            acc1 = __builtin_amdgcn_mfma_f32_16x16x32_bf16(a[s], bfr[1][s], acc1, 0, 0, 0);
        }

#pragma unroll
        for (int i = 0; i < 4; ++i) {
            int row = row0 + sl * 16 + q * 4 + i;
            h[(size_t)row * D + col0 + m16]      = __builtin_bit_cast(unsigned short, (__bf16)acc0[i]);
            h[(size_t)row * D + col0 + 16 + m16] = __builtin_bit_cast(unsigned short, (__bf16)acc1[i]);
        }
    }
}

// ---------------------------------------------------------------------------
// K2: SpMM on bf16 h — ROW-CHUNK: 8 rows per wave, hoisted row_ptr, inner
// loop = R6 structure (4 chains x 16 lanes x 16B, batch-4 gathers, pk-fma).
// ---------------------------------------------------------------------------
#define PKFMA(hv, vv)                                                          \
    _Pragma("unroll")                                                          \
    for (int j = 0; j < 4; ++j) {                                              \
        unsigned int u = (hv)[j];                                              \
        f32x2 f;                                                               \
        f[0] = __builtin_bit_cast(float, u << 16);                             \
        f[1] = __builtin_bit_cast(float, u & 0xFFFF0000u);                     \
        acc2[j] = __builtin_elementwise_fma((f32x2)(vv), f, acc2[j]);          \
    }

__global__ __launch_bounds__(256) void spmm_bf16_rc(
        const unsigned short* __restrict__ h,
        const int* __restrict__ row_ptr,
        const int* __restrict__ cols,
        const float* __restrict__ vals,
        float* __restrict__ out, int n) {
    const int wave = threadIdx.x >> 6;
    const int lane = threadIdx.x & 63;
    const int wid  = blockIdx.x * 4 + wave;
    const int rbeg = wid * RCHUNK;
    if (rbeg >= n) return;

    const int chain = lane >> 4;    // 4 edge chains, stride 4
    const int l4    = lane & 15;    // 16B slot: dims [l4*8, l4*8+8)

    // one coalesced load covers row_ptr[rbeg .. rbeg+RCHUNK] for this wave
    int idx  = rbeg + (lane < RCHUNK + 1 ? lane : RCHUNK);
    if (idx > n) idx = n;
    const int rp_l = row_ptr[idx];

    const u32x4* h4 = (const u32x4*)h;

#pragma unroll 1
    for (int i = 0; i < RCHUNK; ++i) {
        const int r = rbeg + i;
        if (r >= n) break;
        const int start = __shfl(rp_l, i);
        const int end   = __shfl(rp_l, i + 1);

        f32x2 acc2[4];
#pragma unroll
        for (int j = 0; j < 4; ++j) acc2[j] = (f32x2)0.f;

        const int last = end - 1;
        int e = start + chain;
        while (e < end) {
            int i1 = (e + 4  <= last) ? e + 4  : last;
            int i2 = (e + 8  <= last) ? e + 8  : last;
            int i3 = (e + 12 <= last) ? e + 12 : last;
            int   c0 = cols[e],  c1 = cols[i1], c2 = cols[i2], c3 = cols[i3];
            float v0 = vals[e];
            float v1 = (e + 4  < end) ? vals[i1] : 0.f;
            float v2 = (e + 8  < end) ? vals[i2] : 0.f;
            float v3 = (e + 12 < end) ? vals[i3] : 0.f;

            u32x4 hv0 = h4[(size_t)c0 * (D / 8) + l4];
            u32x4 hv1 = h4[(size_t)c1 * (D / 8) + l4];
            u32x4 hv2 = h4[(size_t)c2 * (D / 8) + l4];
            u32x4 hv3 = h4[(size_t)c3 * (D / 8) + l4];

            PKFMA(hv0, v0)
            PKFMA(hv1, v1)
            PKFMA(hv2, v2)
            PKFMA(hv3, v3)

            e += 16;
        }

        // combine 4 chains (chain index in lane bits 4,5)
#pragma unroll
        for (int j = 0; j < 4; ++j) {
#pragma unroll
            for (int k = 0; k < 2; ++k) {
                float a = acc2[j][k];
                a += __shfl_xor(a, 16);
                a += __shfl_xor(a, 32);
                acc2[j][k] = a;
            }
        }

        if (chain == 0) {
            float4 o0, o1;
            o0.x = fmaxf(acc2[0][0], 0.f); o0.y = fmaxf(acc2[0][1], 0.f);
            o0.z = fmaxf(acc2[1][0], 0.f); o0.w = fmaxf(acc2[1][1], 0.f);
            o1.x = fmaxf(acc2[2][0], 0.f); o1.y = fmaxf(acc2[2][1], 0.f);
            o1.z = fmaxf(acc2[3][0], 0.f); o1.w = fmaxf(acc2[3][1], 0.f);
            float4* op = (float4*)(out + (size_t)r * D + l4 * 8);
            op[0] = o0; op[1] = o1;
        }
    }
}

// ============================ fallback tiers ===============================
__global__ __launch_bounds__(256) void gemm128(const float* __restrict__ x,
                                               const float* __restrict__ w,
                                               float* __restrict__ h, int n) {
    __shared__ float4 ws4[D * D / 4];
    __shared__ float  xs[GEMM_ROWS][D];
    const int tid  = threadIdx.x;
    const int row0 = blockIdx.x * GEMM_ROWS;
    const float4* w4 = (const float4*)w;
    for (int i = tid; i < D * D / 4; i += 256) ws4[i] = w4[i];
    float4* xs4 = (float4*)&xs[0][0];
    const float4* x4 = (const float4*)x;
    for (int i = tid; i < GEMM_ROWS * D / 4; i += 256) {
        int row = row0 + (i >> 5);
        float4 v = make_float4(0.f, 0.f, 0.f, 0.f);
        if (row < n) v = x4[(size_t)row0 * (D / 4) + i];
        xs4[i] = v;
    }
    __syncthreads();
    const int tx = tid & 31, ty = tid >> 5;
    float4 acc[4];
#pragma unroll
    for (int i = 0; i < 4; ++i) acc[i] = make_float4(0.f, 0.f, 0.f, 0.f);
#pragma unroll 8
    for (int k = 0; k < D; ++k) {
        float4 wv = ws4[k * (D / 4) + tx];
#pragma unroll
        for (int i = 0; i < 4; ++i) {
            float xv = xs[ty * 4 + i][k];
            acc[i].x = fmaf(xv, wv.x, acc[i].x);
            acc[i].y = fmaf(xv, wv.y, acc[i].y);
            acc[i].z = fmaf(xv, wv.z, acc[i].z);
            acc[i].w = fmaf(xv, wv.w, acc[i].w);
        }
    }
#pragma unroll
    for (int i = 0; i < 4; ++i) {
        int row = row0 + ty * 4 + i;
        if (row < n) ((float4*)(h + (size_t)row * D))[tx] = acc[i];
    }
}

__global__ __launch_bounds__(128) void spmm_row(const float* __restrict__ h,
                                                const int* __restrict__ rows,
                                                const int* __restrict__ cols,
                                                const float* __restrict__ vals,
                                                float* __restrict__ out, int n_edges) {
    const int r = blockIdx.x, d = threadIdx.x;
    int lo = 0, hi = n_edges;
    while (lo < hi) { int m = (lo + hi) >> 1; if (rows[m] < r) lo = m + 1; else hi = m; }
    const int start = lo;
    hi = n_edges;
    while (lo < hi) { int m = (lo + hi) >> 1; if (rows[m] <= r) lo = m + 1; else hi = m; }
    const int end = lo;
    float acc = 0.f;
    for (int e = start; e < end; ++e)
        acc = fmaf(vals[e], h[(size_t)cols[e] * D + d], acc);
    out[(size_t)r * D + d] = fmaxf(acc, 0.f);
}

__global__ __launch_bounds__(128) void fused_fallback(
        const float* __restrict__ x, const float* __restrict__ w,
        const int* __restrict__ rows, const int* __restrict__ cols,
        const float* __restrict__ vals, float* __restrict__ out, int n_edges) {
    const int r = blockIdx.x, d = threadIdx.x;
    int lo = 0, hi = n_edges;
    while (lo < hi) { int m = (lo + hi) >> 1; if (rows[m] < r) lo = m + 1; else hi = m; }
    const int start = lo;
    hi = n_edges;
    while (lo < hi) { int m = (lo + hi) >> 1; if (rows[m] <= r) lo = m + 1; else hi = m; }
    const int end = lo;
    float acc = 0.f;
    for (int e = start; e < end; ++e) {
        int c = cols[e]; float v = vals[e];
        float hcd = 0.f;
        for (int k = 0; k < D; ++k)
            hcd = fmaf(x[(size_t)c * D + k], w[(size_t)k * D + d], hcd);
        acc = fmaf(v, hcd, acc);
    }
    out[(size_t)r * D + d] = fmaxf(acc, 0.f);
}

// ===========================================================================
extern "C" void kernel_launch(void* const* d_in, const int* in_sizes, int n_in,
                              void* d_out, int out_size, void* d_ws, size_t ws_size,
                              hipStream_t stream) {
    const float* x    = (const float*)d_in[0];
    const float* w    = (const float*)d_in[1];
    const int*   rows = (const int*)d_in[2];
    const int*   cols = (const int*)d_in[3];
    const float* vals = (const float*)d_in[4];
    float* out = (float*)d_out;

    const int n_nodes = in_sizes[0] / D;              // 50000
    const int n_edges = in_sizes[2];                  // 800000
    const int n_pad   = (n_nodes + 63) & ~63;         // 50048

    const size_t h_bytes  = (size_t)n_pad * D * sizeof(unsigned short);  // 12.8 MB
    const size_t rp_off   = h_bytes;
    const size_t need     = rp_off + (size_t)(n_nodes + 1) * sizeof(int);
    const size_t hf_bytes = (size_t)n_nodes * D * sizeof(float);

    if (ws_size >= need) {
        unsigned short* h  = (unsigned short*)d_ws;
        int*            rp = (int*)((char*)d_ws + rp_off);

        const int gemm_blocks = n_pad / 64;                      // 782
        const int rp_blocks   = (n_edges + 255) / 256;           // 3125
        fused_gemm_rp<<<gemm_blocks + rp_blocks, 256, 0, stream>>>(
            x, w, rows, h, rp, n_nodes, n_edges, gemm_blocks);

        const int waves_needed = (n_nodes + RCHUNK - 1) / RCHUNK;
        spmm_bf16_rc<<<(waves_needed + 3) / 4, 256, 0, stream>>>(h, rp, cols, vals, out, n_nodes);
    } else if (ws_size >= hf_bytes) {
        float* hf = (float*)d_ws;
        gemm128<<<(n_nodes + GEMM_ROWS - 1) / GEMM_ROWS, 256, 0, stream>>>(x, w, hf, n_nodes);
        spmm_row<<<n_nodes, 128, 0, stream>>>(hf, rows, cols, vals, out, n_edges);
    } else {
        fused_fallback<<<n_nodes, 128, 0, stream>>>(x, w, rows, cols, vals, out, n_edges);
    }
}